// Round 1
// baseline (409.709 us; speedup 1.0000x reference)
//
#include <hip/hip_runtime.h>
#include <hip/hip_bf16.h>

#define M_TOK 8192
#define N_OUT 4096
#define K_IN  4096

#define BM 128
#define BN 128
#define BK 64

typedef __attribute__((ext_vector_type(8))) short bf16x8;
typedef __attribute__((ext_vector_type(4))) float f32x4;

// fp32 -> bf16 RNE (finite inputs)
__device__ static inline unsigned short f2bf(float f) {
    union { float f; unsigned int u; } v; v.f = f;
    unsigned int u = v.u;
    u += 0x7FFFu + ((u >> 16) & 1u);
    return (unsigned short)(u >> 16);
}

__device__ static inline void load_lds16(const void* g, void* l) {
    __builtin_amdgcn_global_load_lds(
        (const __attribute__((address_space(1))) unsigned int*)g,
        (__attribute__((address_space(3))) unsigned int*)l,
        16, 0, 0);
}

// x fp32 -> bf16, vectorized 4-wide
__global__ void cvt_x_kernel(const float* __restrict__ x,
                             unsigned short* __restrict__ xb, int n4) {
    int i = blockIdx.x * blockDim.x + threadIdx.x;
    int stride = gridDim.x * blockDim.x;
    for (int e = i; e < n4; e += stride) {
        float4 v = reinterpret_cast<const float4*>(x)[e];
        ushort4 o;
        o.x = f2bf(v.x); o.y = f2bf(v.y); o.z = f2bf(v.z); o.w = f2bf(v.w);
        reinterpret_cast<ushort4*>(xb)[e] = o;
    }
}

// w = mean * (1 + noise * |sigma| * sigma_mult), fp32 -> bf16
__global__ void make_w_kernel(const float* __restrict__ mean,
                              const float* __restrict__ sigma,
                              const float* __restrict__ noise,
                              const int* __restrict__ smult,
                              unsigned short* __restrict__ wb, int n4) {
    float sm = (float)(*smult);
    int i = blockIdx.x * blockDim.x + threadIdx.x;
    int stride = gridDim.x * blockDim.x;
    for (int e = i; e < n4; e += stride) {
        float4 m = reinterpret_cast<const float4*>(mean)[e];
        float4 s = reinterpret_cast<const float4*>(sigma)[e];
        float4 z = reinterpret_cast<const float4*>(noise)[e];
        ushort4 o;
        o.x = f2bf(m.x * (1.0f + z.x * fabsf(s.x) * sm));
        o.y = f2bf(m.y * (1.0f + z.y * fabsf(s.y) * sm));
        o.z = f2bf(m.z * (1.0f + z.z * fabsf(s.z) * sm));
        o.w = f2bf(m.w * (1.0f + z.w * fabsf(s.w) * sm));
        reinterpret_cast<ushort4*>(wb)[e] = o;
    }
}

// C[t][o] = sum_k A[t][k] * B[o][k] + bias[o]
// A: [M][K] bf16, B: [N][K] bf16 (both K-contiguous -> identical frag reads)
__global__ __launch_bounds__(256, 2)
void gemm_bias_kernel(const unsigned short* __restrict__ A,
                      const unsigned short* __restrict__ B,
                      const float* __restrict__ bias,
                      float* __restrict__ C) {
    __shared__ unsigned short As[BM * BK];
    __shared__ unsigned short Bs[BN * BK];

    const int tid  = threadIdx.x;
    const int lane = tid & 63;
    const int wid  = tid >> 6;
    const int wr   = wid >> 1;       // wave row (0..1)
    const int wc   = wid & 1;        // wave col (0..1)

    const int brow = blockIdx.x * BM;   // along M (tokens)
    const int bcol = blockIdx.y * BN;   // along N (out features)

    f32x4 acc[4][4];
    #pragma unroll
    for (int m = 0; m < 4; ++m)
        #pragma unroll
        for (int n = 0; n < 4; ++n)
            acc[m][n] = (f32x4){0.f, 0.f, 0.f, 0.f};

    // staging decomposition: thread t loads 16B at LDS linear byte offset
    // p*4096 + t*16 ; global: row = p*32 + t/8, k-chunk = (t%8)*8
    const int srow = tid >> 3;          // 0..31
    const int scol = (tid & 7) * 8;     // 0..56

    const int la_lo = lane & 15;        // frag row/col
    const int la_hi = lane >> 4;        // frag k-chunk selector

    for (int kt = 0; kt < K_IN; kt += BK) {
        #pragma unroll
        for (int p = 0; p < 4; ++p) {
            const unsigned short* g =
                A + (size_t)(brow + p * 32 + srow) * K_IN + kt + scol;
            load_lds16(g, As + p * 2048 + tid * 8);
        }
        #pragma unroll
        for (int p = 0; p < 4; ++p) {
            const unsigned short* g =
                B + (size_t)(bcol + p * 32 + srow) * K_IN + kt + scol;
            load_lds16(g, Bs + p * 2048 + tid * 8);
        }
        __syncthreads();   // compiler emits s_waitcnt vmcnt(0) before barrier

        #pragma unroll
        for (int kk = 0; kk < 2; ++kk) {
            bf16x8 a[4], b[4];
            #pragma unroll
            for (int m = 0; m < 4; ++m)
                a[m] = *reinterpret_cast<const bf16x8*>(
                    As + (wr * 64 + m * 16 + la_lo) * BK + kk * 32 + la_hi * 8);
            #pragma unroll
            for (int n = 0; n < 4; ++n)
                b[n] = *reinterpret_cast<const bf16x8*>(
                    Bs + (wc * 64 + n * 16 + la_lo) * BK + kk * 32 + la_hi * 8);
            #pragma unroll
            for (int m = 0; m < 4; ++m)
                #pragma unroll
                for (int n = 0; n < 4; ++n)
                    acc[m][n] = __builtin_amdgcn_mfma_f32_16x16x32_bf16(
                        a[m], b[n], acc[m][n], 0, 0, 0);
        }
        __syncthreads();
    }

    // epilogue: C/D layout col = lane&15, row = (lane>>4)*4 + r
    const int crow0 = brow + wr * 64;
    const int ccol0 = bcol + wc * 64;
    #pragma unroll
    for (int n = 0; n < 4; ++n) {
        const int col = ccol0 + n * 16 + la_lo;
        const float bv = bias[col];
        #pragma unroll
        for (int m = 0; m < 4; ++m) {
            #pragma unroll
            for (int r = 0; r < 4; ++r) {
                const int row = crow0 + m * 16 + la_hi * 4 + r;
                C[(size_t)row * N_OUT + col] = acc[m][n][r] + bv;
            }
        }
    }
}

extern "C" void kernel_launch(void* const* d_in, const int* in_sizes, int n_in,
                              void* d_out, int out_size, void* d_ws, size_t ws_size,
                              hipStream_t stream) {
    const float* x     = (const float*)d_in[0];
    const float* mean  = (const float*)d_in[1];
    const float* sigma = (const float*)d_in[2];
    const float* bias  = (const float*)d_in[3];
    const float* noise = (const float*)d_in[4];
    const int*   smult = (const int*)d_in[5];
    float* out = (float*)d_out;

    const size_t x_elems = (size_t)M_TOK * K_IN;   // 33554432
    const size_t w_elems = (size_t)N_OUT * K_IN;   // 16777216
    const size_t need = (x_elems + w_elems) * sizeof(unsigned short); // 96 MiB
    if (ws_size < need) return;  // fail loudly via validation rather than corrupt

    unsigned short* xb = (unsigned short*)d_ws;
    unsigned short* wb = xb + x_elems;

    cvt_x_kernel<<<2048, 256, 0, stream>>>(x, xb, (int)(x_elems / 4));
    make_w_kernel<<<2048, 256, 0, stream>>>(mean, sigma, noise, smult, wb,
                                            (int)(w_elems / 4));

    dim3 grid(M_TOK / BM, N_OUT / BN);
    gemm_bias_kernel<<<grid, 256, 0, stream>>>(xb, wb, bias, out);
}

// Round 2
// 330.594 us; speedup vs baseline: 1.2393x; 1.2393x over previous
//
#include <hip/hip_runtime.h>
#include <hip/hip_bf16.h>

#define M_TOK 8192
#define N_OUT 4096
#define K_IN  4096
#define NT    64   // K_IN / 64 K-tiles

typedef __attribute__((ext_vector_type(8))) short bf16x8;
typedef __attribute__((ext_vector_type(4))) float f32x4;
typedef unsigned short u16;

// fp32 -> bf16 RNE (finite inputs)
__device__ static inline u16 f2bf(float f) {
    union { float f; unsigned int u; } v; v.f = f;
    unsigned int u = v.u;
    u += 0x7FFFu + ((u >> 16) & 1u);
    return (u16)(u >> 16);
}

__device__ static inline void load_lds16(const void* g, void* l) {
    __builtin_amdgcn_global_load_lds(
        (const __attribute__((address_space(1))) unsigned int*)g,
        (__attribute__((address_space(3))) unsigned int*)l,
        16, 0, 0);
}

// ---------------- cvt passes (memory-bound, near roofline) ----------------
__global__ void cvt_x_kernel(const float* __restrict__ x,
                             u16* __restrict__ xb, int n4) {
    int i = blockIdx.x * blockDim.x + threadIdx.x;
    int stride = gridDim.x * blockDim.x;
    for (int e = i; e < n4; e += stride) {
        float4 v = reinterpret_cast<const float4*>(x)[e];
        ushort4 o;
        o.x = f2bf(v.x); o.y = f2bf(v.y); o.z = f2bf(v.z); o.w = f2bf(v.w);
        reinterpret_cast<ushort4*>(xb)[e] = o;
    }
}

__global__ void make_w_kernel(const float* __restrict__ mean,
                              const float* __restrict__ sigma,
                              const float* __restrict__ noise,
                              const int* __restrict__ smult,
                              u16* __restrict__ wb, int n4) {
    float sm = (float)(*smult);
    int i = blockIdx.x * blockDim.x + threadIdx.x;
    int stride = gridDim.x * blockDim.x;
    for (int e = i; e < n4; e += stride) {
        float4 m = reinterpret_cast<const float4*>(mean)[e];
        float4 s = reinterpret_cast<const float4*>(sigma)[e];
        float4 z = reinterpret_cast<const float4*>(noise)[e];
        ushort4 o;
        o.x = f2bf(m.x * (1.0f + z.x * fabsf(s.x) * sm));
        o.y = f2bf(m.y * (1.0f + z.y * fabsf(s.y) * sm));
        o.z = f2bf(m.z * (1.0f + z.z * fabsf(s.z) * sm));
        o.w = f2bf(m.w * (1.0f + z.w * fabsf(s.w) * sm));
        reinterpret_cast<ushort4*>(wb)[e] = o;
    }
}

// ---------------- 256x256 8-phase GEMM (T1..T5 stack) ----------------
// C[t][o] = sum_k A[t][k]*B[o][k] + bias[o]; A=[M][K] bf16, B=[N][K] bf16.
// LDS (elements): [buf(2)][op A=0/B=1][half(2)][8192]  = 128 KiB total.
// Swizzle: 16B slot s at row r stored at slot s^(r&7); applied on the
// global SOURCE of global_load_lds (LDS dst stays linear) and on ds_read.

#define BAR()   __builtin_amdgcn_s_barrier()
#define LGKM0() asm volatile("s_waitcnt lgkmcnt(0)" ::: "memory")
#define VMC4()  asm volatile("s_waitcnt vmcnt(4)" ::: "memory")
#define VMC0()  asm volatile("s_waitcnt vmcnt(0)" ::: "memory")

#define DS_A4(AR, MG, AB) \
  _Pragma("unroll") for (int m_ = 0; m_ < 4; ++m_) { \
    AR[m_][0] = *reinterpret_cast<const bf16x8*>((AB) + ((MG)+m_)*1024 + aoff0); \
    AR[m_][1] = *reinterpret_cast<const bf16x8*>((AB) + ((MG)+m_)*1024 + aoff1); }

#define DS_B2(BR, NG, BB) \
  _Pragma("unroll") for (int n_ = 0; n_ < 2; ++n_) { \
    BR[n_][0] = *reinterpret_cast<const bf16x8*>((BB) + ((NG)+n_)*1024 + aoff0); \
    BR[n_][1] = *reinterpret_cast<const bf16x8*>((BB) + ((NG)+n_)*1024 + aoff1); }

#define QUAD(MG, NG, AR, BR) \
  __builtin_amdgcn_s_setprio(1); \
  _Pragma("unroll") for (int m_ = 0; m_ < 4; ++m_) \
  _Pragma("unroll") for (int n_ = 0; n_ < 2; ++n_) { \
    acc[(MG)+m_][(NG)+n_] = __builtin_amdgcn_mfma_f32_16x16x32_bf16( \
        AR[m_][0], BR[n_][0], acc[(MG)+m_][(NG)+n_], 0, 0, 0); \
    acc[(MG)+m_][(NG)+n_] = __builtin_amdgcn_mfma_f32_16x16x32_bf16( \
        AR[m_][1], BR[n_][1], acc[(MG)+m_][(NG)+n_], 0, 0, 0); } \
  __builtin_amdgcn_s_setprio(0);

#define STAGE_A(T, H, BUF) { \
  const u16* g_ = Abase + (size_t)((H)*128 + srow) * K_IN + (T)*64 + sxcol; \
  load_lds16(g_, smem + (BUF)*32768 + (H)*8192 + tid*8); \
  load_lds16(g_ + (size_t)64*K_IN, smem + (BUF)*32768 + (H)*8192 + 4096 + tid*8); }

#define STAGE_B(T, H, BUF) { \
  const u16* g_ = Bbase + (size_t)((H)*128 + srow) * K_IN + (T)*64 + sxcol; \
  load_lds16(g_, smem + (BUF)*32768 + 16384 + (H)*8192 + tid*8); \
  load_lds16(g_ + (size_t)64*K_IN, smem + (BUF)*32768 + 16384 + (H)*8192 + 4096 + tid*8); }

__global__ __launch_bounds__(512, 2)
void gemm_bias_kernel(const u16* __restrict__ A, const u16* __restrict__ B,
                      const float* __restrict__ bias, float* __restrict__ C) {
    __shared__ u16 smem[65536];   // 128 KiB

    const int tid   = threadIdx.x;
    const int lane  = tid & 63;
    const int wid   = tid >> 6;
    const int wm    = wid >> 2;      // 0..1  (M quadrant, 128 rows)
    const int wn    = wid & 3;       // 0..3  (N slice, 64 cols)
    const int la_lo = lane & 15;
    const int la_hi = lane >> 4;

    // T1: bijective XCD swizzle (512 % 8 == 0); bn-major within each XCD
    const int bid  = blockIdx.x;
    const int wgid = (bid & 7) * 64 + (bid >> 3);
    const int bm   = wgid & 31;      // 32 M-blocks
    const int bn   = wgid >> 5;      // 16 N-blocks
    const int brow = bm * 256;
    const int bcol = bn * 256;

    const u16* Abase = A + (size_t)brow * K_IN;
    const u16* Bbase = B + (size_t)bcol * K_IN;

    // staging: thread stages 16B; row = c*64 + tid/8, slot = (tid&7)^(row&7)
    const int srow  = tid >> 3;
    const int sxcol = ((tid & 7) ^ (srow & 7)) * 8;

    // ds_read per-lane offsets (elements): row la_lo, slot (kk*4+la_hi)^(la_lo&7)
    const int xorr  = la_lo & 7;
    const int aoff0 = la_lo * 64 + ((la_hi    ) ^ xorr) * 8;
    const int aoff1 = la_lo * 64 + ((la_hi + 4) ^ xorr) * 8;

    // wave-local LDS half bases (fold (wn&1)*64-row offset into B base)
    const u16* A0 = smem +         wm * 8192;
    const u16* A1 = smem + 32768 + wm * 8192;
    const u16* B0 = smem +         16384 + (wn >> 1) * 8192 + (wn & 1) * 4096;
    const u16* B1 = smem + 32768 + 16384 + (wn >> 1) * 8192 + (wn & 1) * 4096;

    f32x4 acc[8][4];
    #pragma unroll
    for (int m = 0; m < 8; ++m)
        #pragma unroll
        for (int n = 0; n < 4; ++n)
            acc[m][n] = (f32x4){0.f, 0.f, 0.f, 0.f};

    bf16x8 aR[4][2], bA[2][2], bB[2][2];

    // Prologue: tile0 fully (8 loads), tile1 B-halves (4 loads)
    STAGE_B(0, 0, 0); STAGE_B(0, 1, 0);
    STAGE_A(0, 0, 0); STAGE_A(0, 1, 0);
    STAGE_B(1, 0, 1); STAGE_B(1, 1, 1);
    VMC4();           // tile0's 8 loads forced complete; tile1 B may fly
    BAR();

    // Main loop: iteration i computes tiles 2i (buf0) and 2i+1 (buf1),
    // stages Ah(2i+1)@p0/p1, Bh(2i+2)@p2/p3, Ah(2i+2)@p4/p5, Bh(2i+3)@p6/p7.
    for (int i = 0; i < 31; ++i) {
        const int t1 = 2 * i + 1, t2 = 2 * i + 2, t3 = 2 * i + 3;
        // p0
        DS_A4(aR, 0, A0); DS_B2(bA, 0, B0); STAGE_A(t1, 0, 1);
        BAR(); LGKM0(); QUAD(0, 0, aR, bA); BAR();
        // p1
        DS_B2(bB, 2, B0); STAGE_A(t1, 1, 1);
        BAR(); LGKM0(); QUAD(0, 2, aR, bB); BAR();
        // p2
        DS_A4(aR, 4, A0); STAGE_B(t2, 0, 0);
        BAR(); LGKM0(); QUAD(4, 2, aR, bB); BAR();
        // p3  (counted wait: tile 2i+1 must be fully landed for p4 reads)
        STAGE_B(t2, 1, 0);
        BAR(); QUAD(4, 0, aR, bA); VMC4(); BAR();
        // p4
        DS_A4(aR, 0, A1); DS_B2(bA, 0, B1); STAGE_A(t2, 0, 0);
        BAR(); LGKM0(); QUAD(0, 0, aR, bA); BAR();
        // p5
        DS_B2(bB, 2, B1); STAGE_A(t2, 1, 0);
        BAR(); LGKM0(); QUAD(0, 2, aR, bB); BAR();
        // p6
        DS_A4(aR, 4, A1); STAGE_B(t3, 0, 1);
        BAR(); LGKM0(); QUAD(4, 2, aR, bB); BAR();
        // p7  (counted wait: tile 2i+2 must be fully landed for next p0)
        STAGE_B(t3, 1, 1);
        BAR(); QUAD(4, 0, aR, bA); VMC4(); BAR();
    }

    // Peeled last pair: tiles 62 (buf0), 63 (buf1); only Ah(63) left to stage
    DS_A4(aR, 0, A0); DS_B2(bA, 0, B0); STAGE_A(63, 0, 1);
    BAR(); LGKM0(); QUAD(0, 0, aR, bA); BAR();
    DS_B2(bB, 2, B0); STAGE_A(63, 1, 1);
    BAR(); LGKM0(); QUAD(0, 2, aR, bB); BAR();
    DS_A4(aR, 4, A0);
    BAR(); LGKM0(); QUAD(4, 2, aR, bB); BAR();
    BAR(); QUAD(4, 0, aR, bA); VMC0(); BAR();
    DS_A4(aR, 0, A1); DS_B2(bA, 0, B1);
    BAR(); LGKM0(); QUAD(0, 0, aR, bA); BAR();
    DS_B2(bB, 2, B1);
    BAR(); LGKM0(); QUAD(0, 2, aR, bB); BAR();
    DS_A4(aR, 4, A1);
    BAR(); LGKM0(); QUAD(4, 2, aR, bB); BAR();
    QUAD(4, 0, aR, bA);

    // Epilogue: C/D layout col = lane&15, row = (lane>>4)*4 + r; add bias
    const int crow0 = brow + wm * 128;
    const int ccol0 = bcol + wn * 64;
    #pragma unroll
    for (int n = 0; n < 4; ++n) {
        const int col = ccol0 + n * 16 + la_lo;
        const float bv = bias[col];
        #pragma unroll
        for (int m = 0; m < 8; ++m) {
            #pragma unroll
            for (int r = 0; r < 4; ++r) {
                const int row = crow0 + m * 16 + la_hi * 4 + r;
                C[(size_t)row * N_OUT + col] = acc[m][n][r] + bv;
            }
        }
    }
}

extern "C" void kernel_launch(void* const* d_in, const int* in_sizes, int n_in,
                              void* d_out, int out_size, void* d_ws, size_t ws_size,
                              hipStream_t stream) {
    const float* x     = (const float*)d_in[0];
    const float* mean  = (const float*)d_in[1];
    const float* sigma = (const float*)d_in[2];
    const float* bias  = (const float*)d_in[3];
    const float* noise = (const float*)d_in[4];
    const int*   smult = (const int*)d_in[5];
    float* out = (float*)d_out;

    const size_t x_elems = (size_t)M_TOK * K_IN;
    const size_t w_elems = (size_t)N_OUT * K_IN;
    const size_t need = (x_elems + w_elems) * sizeof(u16);
    if (ws_size < need) return;

    u16* xb = (u16*)d_ws;
    u16* wb = xb + x_elems;

    cvt_x_kernel<<<2048, 256, 0, stream>>>(x, xb, (int)(x_elems / 4));
    make_w_kernel<<<2048, 256, 0, stream>>>(mean, sigma, noise, smult, wb,
                                            (int)(w_elems / 4));

    gemm_bias_kernel<<<512, 512, 0, stream>>>(xb, wb, bias, out);
}

// Round 3
// 313.747 us; speedup vs baseline: 1.3059x; 1.0537x over previous
//
#include <hip/hip_runtime.h>
#include <hip/hip_bf16.h>

#define M_TOK 8192
#define N_OUT 4096
#define K_IN  4096
#define NT    64   // K_IN / 64 K-tiles

typedef __attribute__((ext_vector_type(8))) short bf16x8;
typedef __attribute__((ext_vector_type(4))) float f32x4;
typedef unsigned short u16;

// fp32 -> bf16 RNE (finite inputs)
__device__ static inline u16 f2bf(float f) {
    union { float f; unsigned int u; } v; v.f = f;
    unsigned int u = v.u;
    u += 0x7FFFu + ((u >> 16) & 1u);
    return (u16)(u >> 16);
}

__device__ static inline void load_lds16(const void* g, void* l) {
    __builtin_amdgcn_global_load_lds(
        (const __attribute__((address_space(1))) unsigned int*)g,
        (__attribute__((address_space(3))) unsigned int*)l,
        16, 0, 0);
}

// ---------------- fused prep pass (memory-bound, near roofline) -----------
// blocks [0,2048): x fp32->bf16 ; blocks [2048,3072): w = mean*(1+noise*|sigma|*sm)
__global__ void prep_kernel(const float* __restrict__ x,
                            const float* __restrict__ mean,
                            const float* __restrict__ sigma,
                            const float* __restrict__ noise,
                            const int* __restrict__ smult,
                            u16* __restrict__ xb, u16* __restrict__ wb) {
    if (blockIdx.x < 2048) {
        const int n4 = (M_TOK * K_IN) / 4;
        int i = blockIdx.x * blockDim.x + threadIdx.x;
        const int stride = 2048 * 256;
        for (int e = i; e < n4; e += stride) {
            float4 v = reinterpret_cast<const float4*>(x)[e];
            ushort4 o;
            o.x = f2bf(v.x); o.y = f2bf(v.y); o.z = f2bf(v.z); o.w = f2bf(v.w);
            reinterpret_cast<ushort4*>(xb)[e] = o;
        }
    } else {
        const float sm = (float)(*smult);
        const int n4 = (N_OUT * K_IN) / 4;
        int i = (blockIdx.x - 2048) * blockDim.x + threadIdx.x;
        const int stride = 1024 * 256;
        for (int e = i; e < n4; e += stride) {
            float4 m = reinterpret_cast<const float4*>(mean)[e];
            float4 s = reinterpret_cast<const float4*>(sigma)[e];
            float4 z = reinterpret_cast<const float4*>(noise)[e];
            ushort4 o;
            o.x = f2bf(m.x * (1.0f + z.x * fabsf(s.x) * sm));
            o.y = f2bf(m.y * (1.0f + z.y * fabsf(s.y) * sm));
            o.z = f2bf(m.z * (1.0f + z.z * fabsf(s.z) * sm));
            o.w = f2bf(m.w * (1.0f + z.w * fabsf(s.w) * sm));
            reinterpret_cast<ushort4*>(wb)[e] = o;
        }
    }
}

// ---------------- 256x256 8-phase GEMM (T1..T5 stack) ----------------
// C[t][o] = sum_k A[t][k]*B[o][k] + bias[o]; A=[M][K] bf16, B=[N][K] bf16.
// LDS (elements): [buf(2)][op A=0/B=1][half(2)][8192]  = 128 KiB total.
// Swizzle: 16B slot s at row r stored at slot s^(r&7); applied on the
// global SOURCE of global_load_lds (LDS dst stays linear) and on ds_read.

#define BAR()   __builtin_amdgcn_s_barrier()
#define LGKM0() asm volatile("s_waitcnt lgkmcnt(0)" ::: "memory")
#define VMC4()  asm volatile("s_waitcnt vmcnt(4)" ::: "memory")
#define VMC0()  asm volatile("s_waitcnt vmcnt(0)" ::: "memory")

#define DS_A4(AR, MG, AB) \
  _Pragma("unroll") for (int m_ = 0; m_ < 4; ++m_) { \
    AR[m_][0] = *reinterpret_cast<const bf16x8*>((AB) + ((MG)+m_)*1024 + aoff0); \
    AR[m_][1] = *reinterpret_cast<const bf16x8*>((AB) + ((MG)+m_)*1024 + aoff1); }

#define DS_B2(BR, NG, BB) \
  _Pragma("unroll") for (int n_ = 0; n_ < 2; ++n_) { \
    BR[n_][0] = *reinterpret_cast<const bf16x8*>((BB) + ((NG)+n_)*1024 + aoff0); \
    BR[n_][1] = *reinterpret_cast<const bf16x8*>((BB) + ((NG)+n_)*1024 + aoff1); }

#define QUAD(MG, NG, AR, BR) \
  __builtin_amdgcn_s_setprio(1); \
  _Pragma("unroll") for (int m_ = 0; m_ < 4; ++m_) \
  _Pragma("unroll") for (int n_ = 0; n_ < 2; ++n_) { \
    acc[(MG)+m_][(NG)+n_] = __builtin_amdgcn_mfma_f32_16x16x32_bf16( \
        AR[m_][0], BR[n_][0], acc[(MG)+m_][(NG)+n_], 0, 0, 0); \
    acc[(MG)+m_][(NG)+n_] = __builtin_amdgcn_mfma_f32_16x16x32_bf16( \
        AR[m_][1], BR[n_][1], acc[(MG)+m_][(NG)+n_], 0, 0, 0); } \
  __builtin_amdgcn_s_setprio(0);

#define STAGE_A(T, H, BUF) { \
  const u16* g_ = Abase + (size_t)((H)*128 + srow) * K_IN + (T)*64 + sxcol; \
  load_lds16(g_, smem + (BUF)*32768 + (H)*8192 + tid*8); \
  load_lds16(g_ + (size_t)64*K_IN, smem + (BUF)*32768 + (H)*8192 + 4096 + tid*8); }

#define STAGE_B(T, H, BUF) { \
  const u16* g_ = Bbase + (size_t)((H)*128 + srow) * K_IN + (T)*64 + sxcol; \
  load_lds16(g_, smem + (BUF)*32768 + 16384 + (H)*8192 + tid*8); \
  load_lds16(g_ + (size_t)64*K_IN, smem + (BUF)*32768 + 16384 + (H)*8192 + 4096 + tid*8); }

__global__ __launch_bounds__(512, 2)
void gemm_bias_kernel(const u16* __restrict__ A, const u16* __restrict__ B,
                      const float* __restrict__ bias, float* __restrict__ C) {
    __shared__ u16 smem[65536];   // 128 KiB

    const int tid   = threadIdx.x;
    const int lane  = tid & 63;
    const int wid   = tid >> 6;
    const int wm    = wid >> 2;      // 0..1  (M quadrant, 128 rows)
    const int wn    = wid & 3;       // 0..3  (N slice, 64 cols)
    const int la_lo = lane & 15;
    const int la_hi = lane >> 4;

    // T1 v2: per-XCD 2D rectangle. HW maps bid%8 -> XCD. Each XCD-round
    // (32 concurrent blocks) covers a 4bm x 8bn rectangle so concurrent
    // blocks share panel K-slices in L2 (~384 KB active << 4 MiB L2).
    // Bijective: 16 rects = 8 xcd x 2 rounds.
    const int bid = blockIdx.x;
    const int xcd = bid & 7;
    const int c   = bid >> 3;        // 0..63 (dispatch order within XCD)
    const int r   = c >> 5;          // round 0..1
    const int s   = c & 31;
    const int bm  = xcd * 4 + (s & 3);    // 0..31
    const int bn  = r * 8 + (s >> 2);     // 0..15
    const int brow = bm * 256;
    const int bcol = bn * 256;

    const u16* Abase = A + (size_t)brow * K_IN;
    const u16* Bbase = B + (size_t)bcol * K_IN;

    // staging: thread stages 16B; row = c*64 + tid/8, slot = (tid&7)^(row&7)
    const int srow  = tid >> 3;
    const int sxcol = ((tid & 7) ^ (srow & 7)) * 8;

    // ds_read per-lane offsets (elements): row la_lo, slot (kk*4+la_hi)^(la_lo&7)
    const int xorr  = la_lo & 7;
    const int aoff0 = la_lo * 64 + ((la_hi    ) ^ xorr) * 8;
    const int aoff1 = la_lo * 64 + ((la_hi + 4) ^ xorr) * 8;

    // wave-local LDS half bases (fold (wn&1)*64-row offset into B base)
    const u16* A0 = smem +         wm * 8192;
    const u16* A1 = smem + 32768 + wm * 8192;
    const u16* B0 = smem +         16384 + (wn >> 1) * 8192 + (wn & 1) * 4096;
    const u16* B1 = smem + 32768 + 16384 + (wn >> 1) * 8192 + (wn & 1) * 4096;

    f32x4 acc[8][4];
    #pragma unroll
    for (int m = 0; m < 8; ++m)
        #pragma unroll
        for (int n = 0; n < 4; ++n)
            acc[m][n] = (f32x4){0.f, 0.f, 0.f, 0.f};

    bf16x8 aR[4][2], bA[2][2], bB[2][2];

    // Prologue: tile0 fully (8 loads), tile1 B-halves (4 loads)
    STAGE_B(0, 0, 0); STAGE_B(0, 1, 0);
    STAGE_A(0, 0, 0); STAGE_A(0, 1, 0);
    STAGE_B(1, 0, 1); STAGE_B(1, 1, 1);
    VMC4();           // tile0's 8 loads forced complete; tile1 B may fly
    BAR();

    // Main loop: iteration i computes tiles 2i (buf0) and 2i+1 (buf1),
    // stages Ah(2i+1)@p0/p1, Bh(2i+2)@p2/p3, Ah(2i+2)@p4/p5, Bh(2i+3)@p6/p7.
    for (int i = 0; i < 31; ++i) {
        const int t1 = 2 * i + 1, t2 = 2 * i + 2, t3 = 2 * i + 3;
        // p0
        DS_A4(aR, 0, A0); DS_B2(bA, 0, B0); STAGE_A(t1, 0, 1);
        BAR(); LGKM0(); QUAD(0, 0, aR, bA); BAR();
        // p1
        DS_B2(bB, 2, B0); STAGE_A(t1, 1, 1);
        BAR(); LGKM0(); QUAD(0, 2, aR, bB); BAR();
        // p2
        DS_A4(aR, 4, A0); STAGE_B(t2, 0, 0);
        BAR(); LGKM0(); QUAD(4, 2, aR, bB); BAR();
        // p3  (counted wait: tile 2i+1 fully landed before p4 reads)
        STAGE_B(t2, 1, 0);
        BAR(); QUAD(4, 0, aR, bA); VMC4(); BAR();
        // p4
        DS_A4(aR, 0, A1); DS_B2(bA, 0, B1); STAGE_A(t2, 0, 0);
        BAR(); LGKM0(); QUAD(0, 0, aR, bA); BAR();
        // p5
        DS_B2(bB, 2, B1); STAGE_A(t2, 1, 0);
        BAR(); LGKM0(); QUAD(0, 2, aR, bB); BAR();
        // p6
        DS_A4(aR, 4, A1); STAGE_B(t3, 0, 1);
        BAR(); LGKM0(); QUAD(4, 2, aR, bB); BAR();
        // p7  (counted wait: tile 2i+2 fully landed before next p0 reads)
        STAGE_B(t3, 1, 1);
        BAR(); QUAD(4, 0, aR, bA); VMC4(); BAR();
    }

    // Peeled last pair: tiles 62 (buf0), 63 (buf1); only Ah(63) left to stage
    DS_A4(aR, 0, A0); DS_B2(bA, 0, B0); STAGE_A(63, 0, 1);
    BAR(); LGKM0(); QUAD(0, 0, aR, bA); BAR();
    DS_B2(bB, 2, B0); STAGE_A(63, 1, 1);
    BAR(); LGKM0(); QUAD(0, 2, aR, bB); BAR();
    DS_A4(aR, 4, A0);
    BAR(); LGKM0(); QUAD(4, 2, aR, bB); BAR();
    BAR(); QUAD(4, 0, aR, bA); VMC0(); BAR();
    DS_A4(aR, 0, A1); DS_B2(bA, 0, B1);
    BAR(); LGKM0(); QUAD(0, 0, aR, bA); BAR();
    DS_B2(bB, 2, B1);
    BAR(); LGKM0(); QUAD(0, 2, aR, bB); BAR();
    DS_A4(aR, 4, A1);
    BAR(); LGKM0(); QUAD(4, 2, aR, bB); BAR();
    QUAD(4, 0, aR, bA);

    // Epilogue: C/D layout col = lane&15, row = (lane>>4)*4 + r; add bias
    const int crow0 = brow + wm * 128;
    const int ccol0 = bcol + wn * 64;
    #pragma unroll
    for (int n = 0; n < 4; ++n) {
        const int col = ccol0 + n * 16 + la_lo;
        const float bv = bias[col];
        #pragma unroll
        for (int m = 0; m < 8; ++m) {
            #pragma unroll
            for (int rr = 0; rr < 4; ++rr) {
                const int row = crow0 + m * 16 + la_hi * 4 + rr;
                C[(size_t)row * N_OUT + col] = acc[m][n][rr] + bv;
            }
        }
    }
}

extern "C" void kernel_launch(void* const* d_in, const int* in_sizes, int n_in,
                              void* d_out, int out_size, void* d_ws, size_t ws_size,
                              hipStream_t stream) {
    const float* x     = (const float*)d_in[0];
    const float* mean  = (const float*)d_in[1];
    const float* sigma = (const float*)d_in[2];
    const float* bias  = (const float*)d_in[3];
    const float* noise = (const float*)d_in[4];
    const int*   smult = (const int*)d_in[5];
    float* out = (float*)d_out;

    const size_t x_elems = (size_t)M_TOK * K_IN;
    const size_t w_elems = (size_t)N_OUT * K_IN;
    const size_t need = (x_elems + w_elems) * sizeof(u16);
    if (ws_size < need) return;

    u16* xb = (u16*)d_ws;
    u16* wb = xb + x_elems;

    prep_kernel<<<3072, 256, 0, stream>>>(x, mean, sigma, noise, smult, xb, wb);
    gemm_bias_kernel<<<512, 512, 0, stream>>>(xb, wb, bias, out);
}